// Round 9
// baseline (451.854 us; speedup 1.0000x reference)
//
#include <hip/hip_runtime.h>
#include <math.h>

#define Nn 1024
#define Ee 4
#define Uu 32
#define BLOCK_ROWS 32  // 4 waves x 8 rows

// ---------------------------------------------------------------------------
// pre-kernel: grid (128, 5), block 256. blockIdx.y = e (0..3 edge types,
// 4 = residual W2/b2).
//   e<4 : hpre_t[b][e][u][n] = sum_f ann[b,n,f]*Wa[e,f,u] + ba[e,u]  (u-major!)
//   e==4: res[b][n][u]       = sum_f ann[b,n,f]*W2[f,u]  + b2[u]
// ---------------------------------------------------------------------------
template <int F, int FA>
__global__ __launch_bounds__(256) void pre_kernel(
    const float* __restrict__ annA, const float* __restrict__ annB,
    const float* __restrict__ Wa, const float* __restrict__ ba,
    const float* __restrict__ W2, const float* __restrict__ b2,
    float* __restrict__ hpre_t, float* __restrict__ res)
{
    const int e = blockIdx.y;            // 0..4
    __shared__ float wlds[F * Uu];
    __shared__ float blds[Uu];
    const int tid = threadIdx.x;
    const float* wsrc = (e < 4) ? (Wa + (size_t)e * F * Uu) : W2;
    const float* bsrc = (e < 4) ? (ba + (size_t)e * Uu) : b2;
    for (int i = tid; i < F * Uu; i += 256) wlds[i] = wsrc[i];
    if (tid < Uu) blds[tid] = bsrc[tid];
    __syncthreads();

    const int g = blockIdx.x * 256 + tid;   // flat row in [0, B*N)
    const int b = g >> 10;
    const int n = g & 1023;

    float4 a4[F / 4];
    {
        const float4* rA = (const float4*)(annA + (size_t)g * FA);
#pragma unroll
        for (int i = 0; i < FA / 4; ++i) a4[i] = rA[i];
        if constexpr (F > FA) {
            const float4* rB = (const float4*)(annB + (size_t)g * (F - FA));
#pragma unroll
            for (int i = 0; i < (F - FA) / 4; ++i) a4[FA / 4 + i] = rB[i];
        }
    }

    float4 acc[8];
    const float4* bb = (const float4*)blds;
#pragma unroll
    for (int uq = 0; uq < 8; ++uq) acc[uq] = bb[uq];
    const float4* w4 = (const float4*)wlds;
#pragma unroll
    for (int f4 = 0; f4 < F / 4; ++f4) {
        const float4 av = a4[f4];
#pragma unroll
        for (int c = 0; c < 4; ++c) {
            const float s = (c == 0) ? av.x : (c == 1) ? av.y : (c == 2) ? av.z : av.w;
#pragma unroll
            for (int uq = 0; uq < 8; ++uq) {
                const float4 w = w4[(f4 * 4 + c) * 8 + uq];  // uniform -> broadcast
                acc[uq].x = fmaf(s, w.x, acc[uq].x);
                acc[uq].y = fmaf(s, w.y, acc[uq].y);
                acc[uq].z = fmaf(s, w.z, acc[uq].z);
                acc[uq].w = fmaf(s, w.w, acc[uq].w);
            }
        }
    }
    if (e < 4) {
        float* dst = hpre_t + ((size_t)(b * 4 + e) * Uu) * Nn + n;  // [b][e][u][n]
#pragma unroll
        for (int uq = 0; uq < 8; ++uq) {
            dst[(uq * 4 + 0) * Nn] = acc[uq].x;
            dst[(uq * 4 + 1) * Nn] = acc[uq].y;
            dst[(uq * 4 + 2) * Nn] = acc[uq].z;
            dst[(uq * 4 + 3) * Nn] = acc[uq].w;
        }
    } else {
        float4* dst = (float4*)(res + (size_t)g * Uu);
#pragma unroll
        for (int uq = 0; uq < 8; ++uq) dst[uq] = acc[uq];
    }
}

// ---------------------------------------------------------------------------
// main kernel: out[b][n][u] = tanh( sum_e sum_m adj[b,e,n,m]*h_pre[b,e,m,u]
//                                   + res[b,n,u] )
// NO LDS, NO barriers, NO asm waits. Each wave is a fully independent
// global->reg->FMA stream:
//   lane (gu, ms) holds adj rows [wrow..wrow+8) x float4 at m-quad ms, and
//   h rows u = gu*8..gu*8+8 x the same float4 m-quad (disjoint across lanes;
//   h[b] = 512 KB is L2-resident, 4 b's per XCD after the swizzle).
// Distance-1 prefetch with STATIC rotating register buffers (avA/hvA vs
// avB/hvB, period-2 macro unroll): body(t) issues t+1 into ALT then computes
// CUR. The compiler emits counted per-use vmcnt for this pure register
// stream, so loads of t+1 stay in flight across compute(t) and waves drift
// freely (no convoy effect). In-flight adj ~ 8 waves x 8 KB >> the ~9 KB/CU
// needed to hide ~900 cy HBM latency -> HBM-bound by construction.
// Epilogue: shfl_xor reduce over the 16 ms lanes + residual + tanh.
// NOTE (R6/R7 lesson): no launch_bounds minimum -- a forced VGPR squeeze
// serializes the load stream or spills it to scratch.
// ---------------------------------------------------------------------------
__global__ __launch_bounds__(256) void gcn_main_kernel(
    const float* __restrict__ adj,     // [B,E,N,N]
    const float* __restrict__ hpre_t,  // [B,E,U,N]
    const float* __restrict__ res,     // [B,N,U]
    float* __restrict__ out)           // [B,N,U]
{
    const int bid = blockIdx.x;                       // 1024 blocks
    const int swz = (bid & 7) * 128 + (bid >> 3);     // XCD-aware, bijective
    const int b = swz >> 5;                           // 32 blocks per b, same XCD
    const int n0 = (swz & 31) * BLOCK_ROWS;
    const int tid = threadIdx.x;
    const int w = tid >> 6;       // wave 0..3
    const int lane = tid & 63;
    const int gu = lane >> 4;     // u-octet 0..3
    const int ms = lane & 15;     // m-quad 0..15
    const int wrow = n0 + w * 8;  // 8 rows per wave

    const float* adjb = adj + (size_t)b * Ee * Nn * Nn;
    const float* hpb  = hpre_t + (size_t)b * Ee * Uu * Nn;

    float acc[8][8];
#pragma unroll
    for (int r = 0; r < 8; ++r)
#pragma unroll
        for (int j = 0; j < 8; ++j) acc[r][j] = 0.f;

    float4 avA[8], avB[8], hvA[8], hvB[8];

    // issue iter T's loads: adj rows first (first-needed), then h rows
#define ISSUE(AV, HV, T)                                                        \
    {                                                                           \
        const int e_ = (T) >> 4, c_ = (T) & 15;                                 \
        const float* ap_ = adjb + ((size_t)e_ * Nn + wrow) * Nn + c_ * 64 + ms * 4; \
        _Pragma("unroll")                                                       \
        for (int r = 0; r < 8; ++r) AV[r] = *(const float4*)(ap_ + (size_t)r * Nn); \
        const float* hp_ = hpb + ((size_t)e_ * Uu + gu * 8) * Nn + c_ * 64 + ms * 4; \
        _Pragma("unroll")                                                       \
        for (int j = 0; j < 8; ++j) HV[j] = *(const float4*)(hp_ + (size_t)j * Nn); \
    }

#define COMPUTE(AV, HV)                                                         \
    {                                                                           \
        _Pragma("unroll")                                                       \
        for (int j = 0; j < 8; ++j) {                                           \
            _Pragma("unroll")                                                   \
            for (int r = 0; r < 8; ++r) {                                       \
                float t0 = fmaf(AV[r].x, HV[j].x, acc[r][j]);                   \
                t0 = fmaf(AV[r].y, HV[j].y, t0);                                \
                t0 = fmaf(AV[r].z, HV[j].z, t0);                                \
                acc[r][j] = fmaf(AV[r].w, HV[j].w, t0);                         \
            }                                                                   \
        }                                                                       \
    }

    // Body(t): issue t+1 into ALT buffers, then compute t from CUR buffers.
#define BODY(T, AVC, HVC, AVN, HVN)                                             \
    {                                                                           \
        const int tn_ = ((T) < 63) ? (T) + 1 : 63;                              \
        ISSUE(AVN, HVN, tn_);                                                   \
        COMPUTE(AVC, HVC);                                                      \
    }

    ISSUE(avA, hvA, 0);   // prologue

    for (int t = 0; t < 64; t += 2) {
        BODY(t + 0, avA, hvA, avB, hvB);
        BODY(t + 1, avB, hvB, avA, hvA);
    }

#undef BODY
#undef ISSUE
#undef COMPUTE

    // reduce partial sums across the 16 ms lanes (lane bits 0..3)
#pragma unroll
    for (int r = 0; r < 8; ++r)
#pragma unroll
        for (int j = 0; j < 8; ++j) {
            float v = acc[r][j];
            v += __shfl_xor(v, 1);
            v += __shfl_xor(v, 2);
            v += __shfl_xor(v, 4);
            v += __shfl_xor(v, 8);
            acc[r][j] = v;
        }

    // epilogue: lane ms==r writes row wrow+r (static acc indexing via unroll)
#pragma unroll
    for (int r = 0; r < 8; ++r) {
        if (ms == r) {
            const int n = wrow + r;
            const float* rp = res + ((size_t)b * Nn + n) * Uu + gu * 8;
            float* op = out + ((size_t)b * Nn + n) * Uu + gu * 8;
            const float4 r0 = *(const float4*)(rp);
            const float4 r1 = *(const float4*)(rp + 4);
            float4 o0, o1;
            o0.x = tanhf(acc[r][0] + r0.x);
            o0.y = tanhf(acc[r][1] + r0.y);
            o0.z = tanhf(acc[r][2] + r0.z);
            o0.w = tanhf(acc[r][3] + r0.w);
            o1.x = tanhf(acc[r][4] + r1.x);
            o1.y = tanhf(acc[r][5] + r1.y);
            o1.z = tanhf(acc[r][6] + r1.z);
            o1.w = tanhf(acc[r][7] + r1.w);
            *(float4*)(op) = o0;
            *(float4*)(op + 4) = o1;
        }
    }
}

extern "C" void kernel_launch(void* const* d_in, const int* in_sizes, int n_in,
                              void* d_out, int out_size, void* d_ws, size_t ws_size,
                              hipStream_t stream)
{
    const float* n_tensor = (const float*)d_in[0];  // [32,1024,32]
    const float* adj      = (const float*)d_in[1];  // [32,4,1024,1024]
    const float* W_adj0   = (const float*)d_in[2];  // [4,32,32]
    const float* b_adj0   = (const float*)d_in[3];  // [4,32]
    const float* W2_0     = (const float*)d_in[4];  // [32,32]
    const float* b2_0     = (const float*)d_in[5];  // [32]
    const float* W_adj1   = (const float*)d_in[6];  // [4,64,32]
    const float* b_adj1   = (const float*)d_in[7];  // [4,32]
    const float* W2_1     = (const float*)d_in[8];  // [64,32]
    const float* b2_1     = (const float*)d_in[9];  // [32]
    float* outp = (float*)d_out;

    float* ws   = (float*)d_ws;
    float* hpre = ws;                            // 16 MiB
    float* resb = ws + (size_t)4 * 1024 * 1024;  // 4 MiB
    float* h0   = ws + (size_t)5 * 1024 * 1024;  // 4 MiB

    dim3 pre_grid(128, 5);

    // layer 0 (F = 32)
    pre_kernel<32, 32><<<pre_grid, 256, 0, stream>>>(n_tensor, nullptr, W_adj0, b_adj0,
                                                     W2_0, b2_0, hpre, resb);
    gcn_main_kernel<<<1024, 256, 0, stream>>>(adj, hpre, resb, h0);

    // layer 1 (F = 64, ann = concat(n_tensor, h0))
    pre_kernel<64, 32><<<pre_grid, 256, 0, stream>>>(n_tensor, h0, W_adj1, b_adj1,
                                                     W2_1, b2_1, hpre, resb);
    gcn_main_kernel<<<1024, 256, 0, stream>>>(adj, hpre, resb, outp);
}